// Round 3
// baseline (14716.042 us; speedup 1.0000x reference)
//
#include <hip/hip_runtime.h>
#include <math.h>
#include <stdint.h>

#define NSEQ 2048
#define D 512
#define V 512
#define NB 8                    // column-slice blocks per chain
#define CPB (D / NB)            // 64 cols per slice
#define NROLE_RNN (2 * NB)      // 8 RNN1 + 8 RNN2
#define NROLE_CRF NB

#define CRF_TAG 0x8000u         // csync aliases sync1; tags disjoint

// ---------------------------------------------------------------------------
// tagged (tag<<32 | float) sync slots. publish: relaxed agent-scope store
// (writes through local L2 to IF$ -> visible everywhere, fast in local L2).
// poll: sc0 load (L1-bypass, L2-hit ~200cy) with periodic agent-scope
// fallback (IF$, guaranteed visibility) -> correct for ANY block placement.
// ---------------------------------------------------------------------------
__device__ __forceinline__ void publish(uint64_t* p, float v, uint32_t tag) {
    uint64_t u = ((uint64_t)tag << 32) | (uint64_t)__float_as_uint(v);
    __hip_atomic_store(p, u, __ATOMIC_RELAXED, __HIP_MEMORY_SCOPE_AGENT);
}

__device__ __forceinline__ uint64_t fast_load_u64(const uint64_t* p) {
    uint64_t u;
    asm volatile("global_load_dwordx2 %0, %1, off sc0\n\t"
                 "s_waitcnt vmcnt(0)"
                 : "=v"(u) : "v"(p) : "memory");
    return u;
}

__device__ __forceinline__ float poll2(uint64_t* p, uint32_t tag) {
    while (true) {
#pragma unroll
        for (int it = 0; it < 4; ++it) {
            uint64_t u = fast_load_u64(p);
            if ((uint32_t)(u >> 32) == tag) return __uint_as_float((uint32_t)u);
        }
        uint64_t u = __hip_atomic_load(p, __ATOMIC_RELAXED,
                                       __HIP_MEMORY_SCOPE_AGENT);
        if ((uint32_t)(u >> 32) == tag) return __uint_as_float((uint32_t)u);
    }
}

__device__ __forceinline__ uint64_t rt_clock() {
    uint64_t t;
    asm volatile("s_memrealtime %0\n\ts_waitcnt lgkmcnt(0)" : "=s"(t));
    return t;
}

// Claim one of nroles roles, preferring blocks on XCD 0 (so workers share one
// coherent L2 and the sc0 fast path hits). Non-XCD0 blocks wait briefly; if
// XCD0 can't fill all roles (pathological dispatch), they claim the rest —
// slow-path polling keeps that case correct. Returns -1 -> exit block.
__device__ __forceinline__ int claim_role(int* claim, int nroles) {
    __shared__ int s_role;
    if (threadIdx.x == 0) {
        int xcc = 0;
        asm volatile("s_getreg_b32 %0, hwreg(HW_REG_XCC_ID)" : "=s"(xcc));
        xcc &= 0xF;
        int r = -1;
        if (xcc == 0) {
            int c = __hip_atomic_fetch_add(claim, 1, __ATOMIC_RELAXED,
                                           __HIP_MEMORY_SCOPE_AGENT);
            if (c < nroles) r = c;
        } else {
            const uint64_t t0 = rt_clock();
            while (rt_clock() - t0 < 50000) {   // 500 us @100MHz
                if (__hip_atomic_load(claim, __ATOMIC_RELAXED,
                                      __HIP_MEMORY_SCOPE_AGENT) >= nroles)
                    break;
            }
            if (__hip_atomic_load(claim, __ATOMIC_RELAXED,
                                  __HIP_MEMORY_SCOPE_AGENT) < nroles) {
                int c = __hip_atomic_fetch_add(claim, 1, __ATOMIC_RELAXED,
                                               __HIP_MEMORY_SCOPE_AGENT);
                if (c < nroles) r = c;
            }
        }
        s_role = r;
    }
    __syncthreads();
    return s_role;
}

// ---------------------------------------------------------------------------
// GEMM: out[t][j] = bias[j] + sum_k x[t][k] * W[k][j]
// ---------------------------------------------------------------------------
template <int TM>
__global__ void gemm_rows(const float* __restrict__ src,
                          const int* __restrict__ nums,
                          const float* __restrict__ emb,
                          const float* __restrict__ W,
                          const float* __restrict__ bias,
                          float* __restrict__ out)
{
    __shared__ float xs[TM][D];
    const int tid = threadIdx.x;               // 256
    const int r0 = blockIdx.x * TM;

    for (int m = 0; m < TM; ++m) {
        const int row = r0 + m;
        const float* xr = nums ? (emb + (size_t)nums[row] * D)
                               : (src + (size_t)row * D);
        for (int idx = tid; idx < D; idx += 256) xs[m][idx] = xr[idx];
    }
    __syncthreads();

    const int j0 = tid, j1 = tid + 256;
    float acc0[TM], acc1[TM];
#pragma unroll
    for (int m = 0; m < TM; ++m) { acc0[m] = 0.f; acc1[m] = 0.f; }

    for (int k = 0; k < D; ++k) {
        const float w0 = W[(size_t)k * D + j0];
        const float w1 = W[(size_t)k * D + j1];
#pragma unroll
        for (int m = 0; m < TM; ++m) {
            const float x = xs[m][k];
            acc0[m] += x * w0;
            acc1[m] += x * w1;
        }
    }
    const float bb0 = bias[j0], bb1 = bias[j1];
#pragma unroll
    for (int m = 0; m < TM; ++m) {
        out[(size_t)(r0 + m) * D + j0] = acc0[m] + bb0;
        out[(size_t)(r0 + m) * D + j1] = acc1[m] + bb1;
    }
}

__device__ __forceinline__ float fast_tanh(float x) {
    return 1.0f - 2.0f / (__expf(2.0f * x) + 1.0f);
}

// ---------------------------------------------------------------------------
// Pipelined RNN1 + RNN2, one kernel, 16 worker blocks (roles 0-7: RNN1
// slices; 8-15: RNN2 slices with fused X2 = h1 @ Wxh2 + b2).
//   h1_t = tanh(X1[t] + h1_{t-1} @ Whh1)           -> sync1 (tag = t)
//   h2_t = tanh(b2 + h1_t @ Wxh2 + h2_{t-1} @ Whh2) -> sync2 (tag = t), Hbuf
// ---------------------------------------------------------------------------
__global__ void rnn_pipe(const float* __restrict__ X1,
                         const float* __restrict__ Whh1,
                         const float* __restrict__ Wxh2,
                         const float* __restrict__ Whh2,
                         const float* __restrict__ b2,
                         uint64_t* __restrict__ sync1,
                         uint64_t* __restrict__ sync2,
                         float* __restrict__ Hbuf,
                         int* __restrict__ claim)
{
    __shared__ float h1sh[D];
    __shared__ float h2sh[D];
    __shared__ float part[D];

    const int role = claim_role(claim, NROLE_RNN);
    if (role < 0) return;

    const int tid = threadIdx.x;      // 512
    const int w = tid >> 6, l = tid & 63;
    const int lcol = (w << 3) + (l & 7);
    const bool pub = (l < 8);

    if (role < NB) {
        // ----- RNN1 slice -----
        const int jbase = role * CPB;
        const int gcol = jbase + lcol;
        float wreg[64];
#pragma unroll
        for (int t = 0; t < 64; ++t)
            wreg[t] = Whh1[(size_t)(w * 64 + t) * D + jbase + l];

        for (int s = 0; s < NSEQ; ++s) {
            const float xpre = pub ? X1[(size_t)s * D + gcol] : 0.f;
            if (s == 0) h1sh[tid] = 0.f;
            else        h1sh[tid] = poll2(&sync1[(size_t)(s - 1) * D + tid],
                                          (uint32_t)(s - 1));
            __syncthreads();

            const float4* h4 = (const float4*)&h1sh[w << 6];
            float a0 = 0.f, a1 = 0.f, a2 = 0.f, a3 = 0.f;
#pragma unroll
            for (int t = 0; t < 16; ++t) {
                float4 hv = h4[t];
                a0 += hv.x * wreg[4 * t + 0];
                a1 += hv.y * wreg[4 * t + 1];
                a2 += hv.z * wreg[4 * t + 2];
                a3 += hv.w * wreg[4 * t + 3];
            }
            part[tid] = (a0 + a1) + (a2 + a3);
            __syncthreads();

            if (pub) {
                float sum = 0.f;
#pragma unroll
                for (int ww = 0; ww < 8; ++ww) sum += part[(ww << 6) + lcol];
                publish(&sync1[(size_t)s * D + gcol],
                        fast_tanh(sum + xpre), (uint32_t)s);
            }
        }
    } else {
        // ----- RNN2 slice (fused X2) -----
        const int jbase = (role - NB) * CPB;
        const int gcol = jbase + lcol;
        float wx[64], wh[64];
#pragma unroll
        for (int t = 0; t < 64; ++t) {
            wx[t] = Wxh2[(size_t)(w * 64 + t) * D + jbase + l];
            wh[t] = Whh2[(size_t)(w * 64 + t) * D + jbase + l];
        }
        const float bpre = pub ? b2[gcol] : 0.f;

        for (int s = 0; s < NSEQ; ++s) {
            h1sh[tid] = poll2(&sync1[(size_t)s * D + tid], (uint32_t)s);
            if (s == 0) h2sh[tid] = 0.f;
            else        h2sh[tid] = poll2(&sync2[(size_t)(s - 1) * D + tid],
                                          (uint32_t)(s - 1));
            __syncthreads();

            const float4* x4 = (const float4*)&h1sh[w << 6];
            const float4* h4 = (const float4*)&h2sh[w << 6];
            float a0 = 0.f, a1 = 0.f, a2 = 0.f, a3 = 0.f;
#pragma unroll
            for (int t = 0; t < 16; ++t) {
                float4 xv = x4[t];
                float4 hv = h4[t];
                a0 += xv.x * wx[4 * t + 0] + hv.x * wh[4 * t + 0];
                a1 += xv.y * wx[4 * t + 1] + hv.y * wh[4 * t + 1];
                a2 += xv.z * wx[4 * t + 2] + hv.z * wh[4 * t + 2];
                a3 += xv.w * wx[4 * t + 3] + hv.w * wh[4 * t + 3];
            }
            part[tid] = (a0 + a1) + (a2 + a3);
            __syncthreads();

            if (pub) {
                float sum = 0.f;
#pragma unroll
                for (int ww = 0; ww < 8; ++ww) sum += part[(ww << 6) + lcol];
                const float g = fast_tanh(sum + bpre);
                publish(&sync2[(size_t)s * D + gcol], g, (uint32_t)s);
                Hbuf[(size_t)s * D + gcol] = g;
            }
        }
    }
}

// ---------------------------------------------------------------------------
// ETt[k*V + j] = exp(T[j*V + k])
// ---------------------------------------------------------------------------
__global__ void prep_ET(const float* __restrict__ T, float* __restrict__ ETt)
{
    const int j = blockIdx.x;
    const int k = threadIdx.x;
    ETt[(size_t)k * V + j] = __expf(T[(size_t)j * V + k]);
}

// ---------------------------------------------------------------------------
// CRF backward recursion (exp-domain matvec):
//   c_new[j] = O[i][j] + M + log( sum_k ET[j,k] * exp(c[k]-M) ), M = max(c)
// ---------------------------------------------------------------------------
__global__ void crf_seq(const float* __restrict__ O,
                        const float* __restrict__ ETt,
                        uint64_t* __restrict__ Csync,
                        float* __restrict__ out,
                        int* __restrict__ claim)
{
    __shared__ float esh[V];
    __shared__ float part[V];
    __shared__ float wmax[8];

    const int role = claim_role(claim, NROLE_CRF);
    if (role < 0) return;

    const int tid = threadIdx.x;      // 512
    const int w = tid >> 6, l = tid & 63;
    const int jbase = role * CPB;
    const int lcol = (w << 3) + (l & 7);
    const int gcol = jbase + lcol;
    const bool pub = (l < 8);

    float wreg[64];
#pragma unroll
    for (int t = 0; t < 64; ++t)
        wreg[t] = ETt[(size_t)(w * 64 + t) * V + jbase + l];

    const int nsteps = NSEQ - 1;   // 2047
    const float oEOS = O[(size_t)(NSEQ - 1) * V + 1];
    float creg = (tid == 1) ? oEOS : -1e30f;

    for (int s = 0; s < nsteps; ++s) {
        const int i = nsteps - 1 - s;           // n-2 .. 0
        const float opre = pub ? O[(size_t)i * V + gcol] : 0.f;

        if (s > 0)
            creg = poll2(&Csync[(size_t)(s - 1) * V + tid],
                         CRF_TAG + (uint32_t)(s - 1));

        float mx = creg;
#pragma unroll
        for (int off = 32; off > 0; off >>= 1)
            mx = fmaxf(mx, __shfl_xor(mx, off, 64));
        if (l == 0) wmax[w] = mx;
        __syncthreads();
        float M = wmax[0];
#pragma unroll
        for (int ww = 1; ww < 8; ++ww) M = fmaxf(M, wmax[ww]);

        esh[tid] = __expf(creg - M);
        __syncthreads();

        const float4* e4 = (const float4*)&esh[w << 6];
        float a0 = 0.f, a1 = 0.f, a2 = 0.f, a3 = 0.f;
#pragma unroll
        for (int t = 0; t < 16; ++t) {
            float4 ev = e4[t];
            a0 += ev.x * wreg[4 * t + 0];
            a1 += ev.y * wreg[4 * t + 1];
            a2 += ev.z * wreg[4 * t + 2];
            a3 += ev.w * wreg[4 * t + 3];
        }
        part[tid] = (a0 + a1) + (a2 + a3);
        __syncthreads();

        if (pub) {
            float sum = 0.f;
#pragma unroll
            for (int ww = 0; ww < 8; ++ww) sum += part[(ww << 6) + lcol];
            const float cn = opre + M + __logf(sum);
            if (s < nsteps - 1) {
                publish(&Csync[(size_t)s * V + gcol], cn, CRF_TAG + (uint32_t)s);
            } else if (role == 0 && w == 0 && l == 0) {
                out[0] = cn;   // c0[BOS], col 0
            }
        }
    }
}

// ---------------------------------------------------------------------------
extern "C" void kernel_launch(void* const* d_in, const int* in_sizes, int n_in,
                              void* d_out, int out_size, void* d_ws, size_t ws_size,
                              hipStream_t stream)
{
    const int*   nums = (const int*)d_in[0];
    const float* emb  = (const float*)d_in[1];
    const float* Wxh1 = (const float*)d_in[2];
    const float* Whh1 = (const float*)d_in[3];
    const float* b1   = (const float*)d_in[4];
    const float* Wxh2 = (const float*)d_in[5];
    const float* Whh2 = (const float*)d_in[6];
    const float* b2   = (const float*)d_in[7];
    const float* Wl   = (const float*)d_in[8];
    const float* bl   = (const float*)d_in[9];
    const float* T    = (const float*)d_in[10];
    float* out = (float*)d_out;

    // workspace layout (~30 MB)
    float* Xbuf = (float*)d_ws;                  // [NSEQ*D]  X1
    float* Hbuf = Xbuf + (size_t)NSEQ * D;       // [NSEQ*D]  H
    float* Obuf = Hbuf + (size_t)NSEQ * D;       // [NSEQ*D]  O
    float* ETt  = Obuf + (size_t)NSEQ * D;       // [V*V]
    uint64_t* sync1 = (uint64_t*)(ETt + (size_t)V * V);  // [NSEQ*D] u64
    uint64_t* sync2 = sync1 + (size_t)NSEQ * D;          // [NSEQ*D] u64
    uint64_t* csync = sync1;  // alias: CRF runs after rnn_pipe; tags disjoint
    int* claims = (int*)(sync2 + (size_t)NSEQ * D);      // [2]

    hipMemsetAsync(claims, 0, 2 * sizeof(int), stream);

    // X1 = gather(emb, nums) @ Wxh1 + b1
    gemm_rows<8><<<NSEQ / 8, 256, 0, stream>>>(nullptr, nums, emb, Wxh1, b1, Xbuf);
    // ET transpose + exp (before the long sequential stretch)
    prep_ET<<<V, V, 0, stream>>>(T, ETt);
    // pipelined RNN1+RNN2 (X2 GEMM fused into RNN2)
    rnn_pipe<<<256, 512, 0, stream>>>(Xbuf, Whh1, Wxh2, Whh2, b2,
                                      sync1, sync2, Hbuf, claims + 0);
    // O = H @ Wl + bl
    gemm_rows<8><<<NSEQ / 8, 256, 0, stream>>>(Hbuf, nullptr, nullptr, Wl, bl, Obuf);
    // CRF backward recursion -> out[0]
    crf_seq<<<256, 512, 0, stream>>>(Obuf, ETt, csync, out, claims + 1);
}

// Round 4
// 4660.942 us; speedup vs baseline: 3.1573x; 3.1573x over previous
//
#include <hip/hip_runtime.h>
#include <math.h>
#include <stdint.h>

#define NSEQ 2048
#define D 512
#define V 512
#define NB 8            // column-slice blocks per pipeline stage
#define CPB 64          // D / NB

// ---------------------------------------------------------------------------
// tagged (tag<<32 | float_bits) sync slots, relaxed agent-scope atomics.
// Self-validating: a stale read can only mismatch the tag, never corrupt.
// Harness re-poisons d_ws to 0xAA before every launch -> tags never collide.
// ---------------------------------------------------------------------------
__device__ __forceinline__ void publish(uint64_t* p, float v, uint32_t tag) {
    uint64_t u = ((uint64_t)tag << 32) | (uint64_t)__float_as_uint(v);
    __hip_atomic_store(p, u, __ATOMIC_RELAXED, __HIP_MEMORY_SCOPE_AGENT);
}
__device__ __forceinline__ float poll_get(uint64_t* p, uint32_t tag) {
    while (true) {
        uint64_t u = __hip_atomic_load(p, __ATOMIC_RELAXED,
                                       __HIP_MEMORY_SCOPE_AGENT);
        if ((uint32_t)(u >> 32) == tag) return __uint_as_float((uint32_t)u);
    }
}
// poll two independent slots with both loads kept in flight together
__device__ __forceinline__ void poll_two(uint64_t* p1, uint32_t t1,
                                         uint64_t* p2, uint32_t t2,
                                         float& v1, float& v2) {
    bool g1 = false, g2 = false;
    while (!(g1 && g2)) {
        uint64_t u1 = 0, u2 = 0;
        if (!g1) u1 = __hip_atomic_load(p1, __ATOMIC_RELAXED,
                                        __HIP_MEMORY_SCOPE_AGENT);
        if (!g2) u2 = __hip_atomic_load(p2, __ATOMIC_RELAXED,
                                        __HIP_MEMORY_SCOPE_AGENT);
        if (!g1 && (uint32_t)(u1 >> 32) == t1) {
            v1 = __uint_as_float((uint32_t)u1); g1 = true;
        }
        if (!g2 && (uint32_t)(u2 >> 32) == t2) {
            v2 = __uint_as_float((uint32_t)u2); g2 = true;
        }
    }
}

__device__ __forceinline__ float fast_tanh(float x) {
    return 1.0f - 2.0f / (__expf(2.0f * x) + 1.0f);
}

// partial dot: wave w's k-range [64w,64w+64) against 64 weights in VGPRs
__device__ __forceinline__ float mat_part(const float* sh, const float* wreg,
                                          int w) {
    const float4* v4 = (const float4*)&sh[w << 6];
    float a0 = 0.f, a1 = 0.f, a2 = 0.f, a3 = 0.f;
#pragma unroll
    for (int t = 0; t < 16; ++t) {
        float4 x = v4[t];
        a0 += x.x * wreg[4 * t + 0];
        a1 += x.y * wreg[4 * t + 1];
        a2 += x.z * wreg[4 * t + 2];
        a3 += x.w * wreg[4 * t + 3];
    }
    return (a0 + a1) + (a2 + a3);
}
__device__ __forceinline__ float mat_part2(const float* shx, const float* shh,
                                           const float* wx, const float* wh,
                                           int w) {
    const float4* x4 = (const float4*)&shx[w << 6];
    const float4* h4 = (const float4*)&shh[w << 6];
    float a0 = 0.f, a1 = 0.f, a2 = 0.f, a3 = 0.f;
#pragma unroll
    for (int t = 0; t < 16; ++t) {
        float4 xv = x4[t];
        float4 hv = h4[t];
        a0 += xv.x * wx[4 * t + 0] + hv.x * wh[4 * t + 0];
        a1 += xv.y * wx[4 * t + 1] + hv.y * wh[4 * t + 1];
        a2 += xv.z * wx[4 * t + 2] + hv.z * wh[4 * t + 2];
        a3 += xv.w * wx[4 * t + 3] + hv.w * wh[4 * t + 3];
    }
    return (a0 + a1) + (a2 + a3);
}

// ---------------------------------------------------------------------------
// X1 = gather(emb, nums) @ Wxh1 + b1   (parallel GEMM, runs before the pipe)
// ---------------------------------------------------------------------------
template <int TM>
__global__ void gemm_rows(const int* __restrict__ nums,
                          const float* __restrict__ emb,
                          const float* __restrict__ W,
                          const float* __restrict__ bias,
                          float* __restrict__ out)
{
    __shared__ float xs[TM][D];
    const int tid = threadIdx.x;               // 256
    const int r0 = blockIdx.x * TM;

    for (int m = 0; m < TM; ++m) {
        const float* xr = emb + (size_t)nums[r0 + m] * D;
        for (int idx = tid; idx < D; idx += 256) xs[m][idx] = xr[idx];
    }
    __syncthreads();

    const int j0 = tid, j1 = tid + 256;
    float acc0[TM], acc1[TM];
#pragma unroll
    for (int m = 0; m < TM; ++m) { acc0[m] = 0.f; acc1[m] = 0.f; }

    for (int k = 0; k < D; ++k) {
        const float w0 = W[(size_t)k * D + j0];
        const float w1 = W[(size_t)k * D + j1];
#pragma unroll
        for (int m = 0; m < TM; ++m) {
            const float x = xs[m][k];
            acc0[m] += x * w0;
            acc1[m] += x * w1;
        }
    }
    const float bb0 = bias[j0], bb1 = bias[j1];
#pragma unroll
    for (int m = 0; m < TM; ++m) {
        out[(size_t)(r0 + m) * D + j0] = acc0[m] + bb0;
        out[(size_t)(r0 + m) * D + j1] = acc1[m] + bb1;
    }
}

// expT[i] = exp(T[i])  (row-major, used by forward CRF)
__global__ void prep_exp(const float* __restrict__ T, float* __restrict__ expT)
{
    const int i = blockIdx.x * 512 + threadIdx.x;
    expT[i] = __expf(T[i]);
}

// ---------------------------------------------------------------------------
// 4-stage pipeline, 32 blocks x 512 threads, all concurrent:
//  stage 0 (blk 0-7):  h1_s = tanh(X1[s] + h1_{s-1} @ Whh1)          -> sync1
//  stage 1 (blk 8-15): h2_s = tanh(b2 + h1_s @ Wxh2 + h2_{s-1}@Whh2) -> sync2
//  stage 2 (blk16-23): O[s] = h2_s @ Wl + bl                          -> syncO
//  stage 3 (blk24-31): forward CRF f_s[k]=O[s][k]+LSE_j(f_{s-1}[j]+T[j,k])
//                      (exp-domain matvec, running max M)  -> syncF, out
// Equivalent to the reference backward recursion; out = f_{n-1}[EOS=1].
// ---------------------------------------------------------------------------
__global__ void __launch_bounds__(512, 1)
pipe_all(const float* __restrict__ X1,
         const float* __restrict__ Whh1,
         const float* __restrict__ Wxh2,
         const float* __restrict__ Whh2,
         const float* __restrict__ b2,
         const float* __restrict__ Wl,
         const float* __restrict__ bl,
         const float* __restrict__ expT,
         uint64_t* __restrict__ sync1,
         uint64_t* __restrict__ sync2,
         uint64_t* __restrict__ syncO,
         uint64_t* __restrict__ syncF,
         float* __restrict__ out)
{
    __shared__ float sh1[D];
    __shared__ float sh2[D];
    __shared__ float part[D];
    __shared__ float wmax[8];

    const int tid = threadIdx.x;      // 512
    const int w = tid >> 6, l = tid & 63;
    const int stage = blockIdx.x >> 3;
    const int slice = blockIdx.x & 7;
    const int jbase = slice * CPB;
    const int lcol = (w << 3) + (l & 7);
    const int gcol = jbase + lcol;
    const bool pub = (l < 8);

    if (stage == 0) {
        float wreg[64];
#pragma unroll
        for (int t = 0; t < 64; ++t)
            wreg[t] = Whh1[(size_t)(w * 64 + t) * D + jbase + l];

        for (int s = 0; s < NSEQ; ++s) {
            const float xpre = pub ? X1[(size_t)s * D + gcol] : 0.f;
            if (s == 0) sh1[tid] = 0.f;
            else        sh1[tid] = poll_get(&sync1[(size_t)(s - 1) * D + tid],
                                            (uint32_t)(s - 1));
            __syncthreads();
            part[tid] = mat_part(sh1, wreg, w);
            __syncthreads();
            if (pub) {
                float sum = 0.f;
#pragma unroll
                for (int ww = 0; ww < 8; ++ww) sum += part[(ww << 6) + lcol];
                publish(&sync1[(size_t)s * D + gcol],
                        fast_tanh(sum + xpre), (uint32_t)s);
            }
        }
    } else if (stage == 1) {
        float wx[64], wh[64];
#pragma unroll
        for (int t = 0; t < 64; ++t) {
            wx[t] = Wxh2[(size_t)(w * 64 + t) * D + jbase + l];
            wh[t] = Whh2[(size_t)(w * 64 + t) * D + jbase + l];
        }
        const float bpre = pub ? b2[gcol] : 0.f;

        for (int s = 0; s < NSEQ; ++s) {
            float h1v, h2v;
            if (s == 0) {
                h1v = poll_get(&sync1[tid], 0u);
                h2v = 0.f;
            } else {
                poll_two(&sync1[(size_t)s * D + tid], (uint32_t)s,
                         &sync2[(size_t)(s - 1) * D + tid], (uint32_t)(s - 1),
                         h1v, h2v);
            }
            sh1[tid] = h1v;
            sh2[tid] = h2v;
            __syncthreads();
            part[tid] = mat_part2(sh1, sh2, wx, wh, w);
            __syncthreads();
            if (pub) {
                float sum = 0.f;
#pragma unroll
                for (int ww = 0; ww < 8; ++ww) sum += part[(ww << 6) + lcol];
                publish(&sync2[(size_t)s * D + gcol],
                        fast_tanh(sum + bpre), (uint32_t)s);
            }
        }
    } else if (stage == 2) {
        float wreg[64];
#pragma unroll
        for (int t = 0; t < 64; ++t)
            wreg[t] = Wl[(size_t)(w * 64 + t) * V + jbase + l];
        const float bpre = pub ? bl[gcol] : 0.f;

        for (int s = 0; s < NSEQ; ++s) {
            sh1[tid] = poll_get(&sync2[(size_t)s * D + tid], (uint32_t)s);
            __syncthreads();
            part[tid] = mat_part(sh1, wreg, w);
            __syncthreads();
            if (pub) {
                float sum = 0.f;
#pragma unroll
                for (int ww = 0; ww < 8; ++ww) sum += part[(ww << 6) + lcol];
                publish(&syncO[(size_t)s * V + gcol], sum + bpre, (uint32_t)s);
            }
        }
    } else {
        // forward CRF
        float wreg[64];
#pragma unroll
        for (int t = 0; t < 64; ++t)
            wreg[t] = expT[(size_t)(w * 64 + t) * V + jbase + l];

        // f_0: only BOS(=0) finite, value O[0][BOS]
        float creg;
        if (tid == 0) creg = poll_get(&syncO[0], 0u);
        else          creg = -1e30f;

        for (int s = 1; s < NSEQ; ++s) {
            float opre;
            if (s > 1) {
                poll_two(&syncF[(size_t)(s - 1) * V + tid], (uint32_t)(s - 1),
                         &syncO[(size_t)s * V + gcol], (uint32_t)s,
                         creg, opre);
            } else {
                opre = poll_get(&syncO[(size_t)s * V + gcol], (uint32_t)s);
            }

            // block-wide max of f_{s-1}
            float mx = creg;
#pragma unroll
            for (int off = 32; off > 0; off >>= 1)
                mx = fmaxf(mx, __shfl_xor(mx, off, 64));
            if (l == 0) wmax[w] = mx;
            __syncthreads();
            float M = wmax[0];
#pragma unroll
            for (int ww = 1; ww < 8; ++ww) M = fmaxf(M, wmax[ww]);

            sh1[tid] = __expf(creg - M);
            __syncthreads();
            part[tid] = mat_part(sh1, wreg, w);
            __syncthreads();

            if (pub) {
                float sum = 0.f;
#pragma unroll
                for (int ww = 0; ww < 8; ++ww) sum += part[(ww << 6) + lcol];
                const float cn = opre + M + __logf(sum);
                if (s < NSEQ - 1) {
                    publish(&syncF[(size_t)s * V + gcol], cn, (uint32_t)s);
                } else if (gcol == 1) {
                    out[0] = cn;           // f_{n-1}[EOS=1]
                }
            }
        }
    }
}

// ---------------------------------------------------------------------------
extern "C" void kernel_launch(void* const* d_in, const int* in_sizes, int n_in,
                              void* d_out, int out_size, void* d_ws, size_t ws_size,
                              hipStream_t stream)
{
    const int*   nums = (const int*)d_in[0];
    const float* emb  = (const float*)d_in[1];
    const float* Wxh1 = (const float*)d_in[2];
    const float* Whh1 = (const float*)d_in[3];
    const float* b1   = (const float*)d_in[4];
    const float* Wxh2 = (const float*)d_in[5];
    const float* Whh2 = (const float*)d_in[6];
    const float* b2   = (const float*)d_in[7];
    const float* Wl   = (const float*)d_in[8];
    const float* bl   = (const float*)d_in[9];
    const float* T    = (const float*)d_in[10];
    float* out = (float*)d_out;

    // workspace (~37 MB): X1 4MB + expT 1MB + 4 sync arrays 8MB each
    float* Xbuf = (float*)d_ws;                         // [NSEQ*D]
    float* expT = Xbuf + (size_t)NSEQ * D;              // [V*V]
    uint64_t* sync1 = (uint64_t*)(expT + (size_t)V * V);
    uint64_t* sync2 = sync1 + (size_t)NSEQ * D;
    uint64_t* syncO = sync2 + (size_t)NSEQ * D;
    uint64_t* syncF = syncO + (size_t)NSEQ * V;

    // X1 = gather(emb, nums) @ Wxh1 + b1
    gemm_rows<8><<<NSEQ / 8, 256, 0, stream>>>(nums, emb, Wxh1, b1, Xbuf);
    // elementwise exp(T)
    prep_exp<<<V * V / 512, 512, 0, stream>>>(T, expT);
    // the whole sequential pipeline in one launch
    pipe_all<<<4 * NB, 512, 0, stream>>>(Xbuf, Whh1, Wxh2, Whh2, b2, Wl, bl,
                                         expT, sync1, sync2, syncO, syncF, out);
}

// Round 5
// 4622.304 us; speedup vs baseline: 3.1837x; 1.0084x over previous
//
#include <hip/hip_runtime.h>
#include <math.h>
#include <stdint.h>

#define NSEQ 2048
#define D 512
#define V 512
#define NB 8            // column-slice blocks per pipeline stage
#define CPB 64          // D / NB
#define RING 64         // ring depth (steps) for sync buffers
#define RMASK (RING - 1)
#define ACK_MAGIC 0x0ACEull

// ---------------------------------------------------------------------------
// tagged (tag<<32 | float_bits) sync slots in RING-deep rings, relaxed
// agent-scope atomics. Ring reuse keeps the polled lines resident in IF$
// (they are rewritten every step) -> no per-step HBM cold miss.
// Self-validating: stale slot holds tag s-RING, never matches tag s.
// ---------------------------------------------------------------------------
__device__ __forceinline__ void publish(uint64_t* p, float v, uint32_t tag) {
    uint64_t u = ((uint64_t)tag << 32) | (uint64_t)__float_as_uint(v);
    __hip_atomic_store(p, u, __ATOMIC_RELAXED, __HIP_MEMORY_SCOPE_AGENT);
}
__device__ __forceinline__ float poll_get(uint64_t* p, uint32_t tag) {
    while (true) {
        uint64_t u = __hip_atomic_load(p, __ATOMIC_RELAXED,
                                       __HIP_MEMORY_SCOPE_AGENT);
        if ((uint32_t)(u >> 32) == tag) return __uint_as_float((uint32_t)u);
    }
}
// poll two independent slots, both loads kept in flight together
__device__ __forceinline__ void poll_two(uint64_t* p1, uint32_t t1,
                                         uint64_t* p2, uint32_t t2,
                                         float& v1, float& v2) {
    bool g1 = false, g2 = false;
    while (!(g1 && g2)) {
        uint64_t u1 = 0, u2 = 0;
        if (!g1) u1 = __hip_atomic_load(p1, __ATOMIC_RELAXED,
                                        __HIP_MEMORY_SCOPE_AGENT);
        if (!g2) u2 = __hip_atomic_load(p2, __ATOMIC_RELAXED,
                                        __HIP_MEMORY_SCOPE_AGENT);
        if (!g1 && (uint32_t)(u1 >> 32) == t1) {
            v1 = __uint_as_float((uint32_t)u1); g1 = true;
        }
        if (!g2 && (uint32_t)(u2 >> 32) == t2) {
            v2 = __uint_as_float((uint32_t)u2); g2 = true;
        }
    }
}

// cross-stage consumer progress (flow control for ring reuse).
// Poisoned (0xAA..) slots fail the magic check -> treated as progress 0.
__device__ __forceinline__ void report(uint64_t* p, int s) {
    uint64_t u = (ACK_MAGIC << 48) | (uint32_t)s;
    __hip_atomic_store(p, u, __ATOMIC_RELAXED, __HIP_MEMORY_SCOPE_AGENT);
}
__device__ __forceinline__ void throttle(uint64_t* prog, int s, int& cached) {
    if (s - cached < RING - 4) return;      // margin: overwrite needs >= s-RING
    while (true) {
        int mn = 0x7fffffff;
#pragma unroll
        for (int i = 0; i < NB; ++i) {
            uint64_t u = __hip_atomic_load(&prog[i], __ATOMIC_RELAXED,
                                           __HIP_MEMORY_SCOPE_AGENT);
            int v = ((u >> 48) == ACK_MAGIC) ? (int)(uint32_t)u : 0;
            mn = (v < mn) ? v : mn;
        }
        cached = mn;
        if (s - cached < RING - 4) return;
    }
}

__device__ __forceinline__ float fast_tanh(float x) {
    return 1.0f - 2.0f / (__expf(2.0f * x) + 1.0f);
}

// partial dot: wave w's k-range [64w,64w+64) against 64 weights in VGPRs
__device__ __forceinline__ float mat_part(const float* sh, const float* wreg,
                                          int w) {
    const float4* v4 = (const float4*)&sh[w << 6];
    float a0 = 0.f, a1 = 0.f, a2 = 0.f, a3 = 0.f;
#pragma unroll
    for (int t = 0; t < 16; ++t) {
        float4 x = v4[t];
        a0 += x.x * wreg[4 * t + 0];
        a1 += x.y * wreg[4 * t + 1];
        a2 += x.z * wreg[4 * t + 2];
        a3 += x.w * wreg[4 * t + 3];
    }
    return (a0 + a1) + (a2 + a3);
}
__device__ __forceinline__ float mat_part2(const float* shx, const float* shh,
                                           const float* wx, const float* wh,
                                           int w) {
    const float4* x4 = (const float4*)&shx[w << 6];
    const float4* h4 = (const float4*)&shh[w << 6];
    float a0 = 0.f, a1 = 0.f, a2 = 0.f, a3 = 0.f;
#pragma unroll
    for (int t = 0; t < 16; ++t) {
        float4 xv = x4[t];
        float4 hv = h4[t];
        a0 += xv.x * wx[4 * t + 0] + hv.x * wh[4 * t + 0];
        a1 += xv.y * wx[4 * t + 1] + hv.y * wh[4 * t + 1];
        a2 += xv.z * wx[4 * t + 2] + hv.z * wh[4 * t + 2];
        a3 += xv.w * wx[4 * t + 3] + hv.w * wh[4 * t + 3];
    }
    return (a0 + a1) + (a2 + a3);
}

// ---------------------------------------------------------------------------
// X1 = gather(emb, nums) @ Wxh1 + b1   (parallel GEMM, before the pipe)
// ---------------------------------------------------------------------------
template <int TM>
__global__ void gemm_rows(const int* __restrict__ nums,
                          const float* __restrict__ emb,
                          const float* __restrict__ W,
                          const float* __restrict__ bias,
                          float* __restrict__ out)
{
    __shared__ float xs[TM][D];
    const int tid = threadIdx.x;               // 256
    const int r0 = blockIdx.x * TM;

    for (int m = 0; m < TM; ++m) {
        const float* xr = emb + (size_t)nums[r0 + m] * D;
        for (int idx = tid; idx < D; idx += 256) xs[m][idx] = xr[idx];
    }
    __syncthreads();

    const int j0 = tid, j1 = tid + 256;
    float acc0[TM], acc1[TM];
#pragma unroll
    for (int m = 0; m < TM; ++m) { acc0[m] = 0.f; acc1[m] = 0.f; }

    for (int k = 0; k < D; ++k) {
        const float w0 = W[(size_t)k * D + j0];
        const float w1 = W[(size_t)k * D + j1];
#pragma unroll
        for (int m = 0; m < TM; ++m) {
            const float x = xs[m][k];
            acc0[m] += x * w0;
            acc1[m] += x * w1;
        }
    }
    const float bb0 = bias[j0], bb1 = bias[j1];
#pragma unroll
    for (int m = 0; m < TM; ++m) {
        out[(size_t)(r0 + m) * D + j0] = acc0[m] + bb0;
        out[(size_t)(r0 + m) * D + j1] = acc1[m] + bb1;
    }
}

__global__ void prep_exp(const float* __restrict__ T, float* __restrict__ expT)
{
    const int i = blockIdx.x * 512 + threadIdx.x;
    expT[i] = __expf(T[i]);
}

// ---------------------------------------------------------------------------
// 4-stage pipeline, 32 blocks x 512 threads, all concurrent, ring-buffered:
//  stage 0 (blk 0-7):  h1_s = tanh(X1[s] + h1_{s-1} @ Whh1)           -> ring1
//  stage 1 (blk 8-15): h2_s = tanh(b2 + h1_s @ Wxh2 + h2_{s-1}@Whh2)  -> ring2
//  stage 2 (blk16-23): O[s] = h2_s @ Wl + bl                          -> ringO
//  stage 3 (blk24-31): forward CRF f_s[k]=O[s][k]+LSE_j(f_{s-1}[j]+T[j,k])
// out = f_{n-1}[EOS=1] (forward algorithm == reference backward recursion).
// Each block keeps its OWN 64-col slice in LDS (own[]) -> only 7/8 of each
// vector is polled. Cross-stage consumers report progress for ring reuse.
// ---------------------------------------------------------------------------
__global__ void __launch_bounds__(512, 1)
pipe_all(const float* __restrict__ X1,
         const float* __restrict__ Whh1,
         const float* __restrict__ Wxh2,
         const float* __restrict__ Whh2,
         const float* __restrict__ b2,
         const float* __restrict__ Wl,
         const float* __restrict__ bl,
         const float* __restrict__ expT,
         uint64_t* __restrict__ ring1,
         uint64_t* __restrict__ ring2,
         uint64_t* __restrict__ ringO,
         uint64_t* __restrict__ ringF,
         uint64_t* __restrict__ prog1,   // stage1's consumption of ring1
         uint64_t* __restrict__ prog2,   // stage2's consumption of ring2
         uint64_t* __restrict__ progO,   // stage3's consumption of ringO
         float* __restrict__ out)
{
    __shared__ float sh1[D];
    __shared__ float sh2[D];
    __shared__ float part[D];
    __shared__ float wmax[8];
    __shared__ float own[CPB];

    const int tid = threadIdx.x;      // 512
    const int w = tid >> 6, l = tid & 63;
    const int stage = blockIdx.x >> 3;
    const int slice = blockIdx.x & 7;
    const int jbase = slice * CPB;
    const int lcol = (w << 3) + (l & 7);
    const int gcol = jbase + lcol;
    const bool pub = (l < 8);
    const bool ownr = (tid >= jbase) && (tid < jbase + CPB);
    int cached = 0;

    if (stage == 0) {
        float wreg[64];
#pragma unroll
        for (int t = 0; t < 64; ++t)
            wreg[t] = Whh1[(size_t)(w * 64 + t) * D + jbase + l];

        for (int s = 0; s < NSEQ; ++s) {
            const float xpre = pub ? X1[(size_t)s * D + gcol] : 0.f;
            if (s == 0)      sh1[tid] = 0.f;
            else if (ownr)   sh1[tid] = own[tid - jbase];
            else             sh1[tid] = poll_get(
                                 &ring1[(size_t)((s - 1) & RMASK) * D + tid],
                                 (uint32_t)(s - 1));
            __syncthreads();
            part[tid] = mat_part(sh1, wreg, w);
            __syncthreads();
            if (pub) {
                float sum = 0.f;
#pragma unroll
                for (int ww = 0; ww < 8; ++ww) sum += part[(ww << 6) + lcol];
                const float g = fast_tanh(sum + xpre);
                own[lcol] = g;
                throttle(prog1, s, cached);
                publish(&ring1[(size_t)(s & RMASK) * D + gcol], g, (uint32_t)s);
            }
            __syncthreads();   // protects own[] for next iteration
        }
    } else if (stage == 1) {
        float wx[64], wh[64];
#pragma unroll
        for (int t = 0; t < 64; ++t) {
            wx[t] = Wxh2[(size_t)(w * 64 + t) * D + jbase + l];
            wh[t] = Whh2[(size_t)(w * 64 + t) * D + jbase + l];
        }
        const float bpre = pub ? b2[gcol] : 0.f;

        for (int s = 0; s < NSEQ; ++s) {
            float h1v, h2v;
            if (s == 0) {
                h1v = poll_get(&ring1[tid], 0u);
                h2v = 0.f;
            } else if (ownr) {
                h2v = own[tid - jbase];
                h1v = poll_get(&ring1[(size_t)(s & RMASK) * D + tid],
                               (uint32_t)s);
            } else {
                poll_two(&ring1[(size_t)(s & RMASK) * D + tid], (uint32_t)s,
                         &ring2[(size_t)((s - 1) & RMASK) * D + tid],
                         (uint32_t)(s - 1), h1v, h2v);
            }
            sh1[tid] = h1v;
            sh2[tid] = h2v;
            __syncthreads();
            part[tid] = mat_part2(sh1, sh2, wx, wh, w);
            __syncthreads();
            if (pub) {
                float sum = 0.f;
#pragma unroll
                for (int ww = 0; ww < 8; ++ww) sum += part[(ww << 6) + lcol];
                const float g = fast_tanh(sum + bpre);
                own[lcol] = g;
                throttle(prog2, s, cached);
                publish(&ring2[(size_t)(s & RMASK) * D + gcol], g, (uint32_t)s);
            }
            if (tid == 0 && (s & 15) == 15) report(&prog1[slice], s);
            __syncthreads();
        }
    } else if (stage == 2) {
        float wreg[64];
#pragma unroll
        for (int t = 0; t < 64; ++t)
            wreg[t] = Wl[(size_t)(w * 64 + t) * V + jbase + l];
        const float bpre = pub ? bl[gcol] : 0.f;

        for (int s = 0; s < NSEQ; ++s) {
            sh1[tid] = poll_get(&ring2[(size_t)(s & RMASK) * D + tid],
                                (uint32_t)s);
            __syncthreads();
            part[tid] = mat_part(sh1, wreg, w);
            __syncthreads();
            if (pub) {
                float sum = 0.f;
#pragma unroll
                for (int ww = 0; ww < 8; ++ww) sum += part[(ww << 6) + lcol];
                throttle(progO, s, cached);
                publish(&ringO[(size_t)(s & RMASK) * V + gcol],
                        sum + bpre, (uint32_t)s);
            }
            if (tid == 0 && (s & 15) == 15) report(&prog2[slice], s);
            __syncthreads();
        }
    } else {
        // forward CRF
        float wreg[64];
#pragma unroll
        for (int t = 0; t < 64; ++t)
            wreg[t] = expT[(size_t)(w * 64 + t) * V + jbase + l];

        // f_0: only BOS(=0) finite, value O[0][BOS]
        float creg = (tid == 0) ? poll_get(&ringO[0], 0u) : -1e30f;

        for (int s = 1; s < NSEQ; ++s) {
            if (s > 1) {
                if (ownr) creg = own[tid - jbase];
                else      creg = poll_get(
                              &ringF[(size_t)((s - 1) & RMASK) * V + tid],
                              (uint32_t)(s - 1));
            }
            const float opre = pub
                ? poll_get(&ringO[(size_t)(s & RMASK) * V + gcol], (uint32_t)s)
                : 0.f;

            // block-wide max of f_{s-1}
            float mx = creg;
#pragma unroll
            for (int off = 32; off > 0; off >>= 1)
                mx = fmaxf(mx, __shfl_xor(mx, off, 64));
            if (l == 0) wmax[w] = mx;
            __syncthreads();
            float M = wmax[0];
#pragma unroll
            for (int ww = 1; ww < 8; ++ww) M = fmaxf(M, wmax[ww]);

            sh1[tid] = __expf(creg - M);
            __syncthreads();
            part[tid] = mat_part(sh1, wreg, w);
            __syncthreads();

            if (pub) {
                float sum = 0.f;
#pragma unroll
                for (int ww = 0; ww < 8; ++ww) sum += part[(ww << 6) + lcol];
                const float cn = opre + M + __logf(sum);
                if (s < NSEQ - 1) {
                    own[lcol] = cn;
                    publish(&ringF[(size_t)(s & RMASK) * V + gcol],
                            cn, (uint32_t)s);
                } else if (gcol == 1) {
                    out[0] = cn;           // f_{n-1}[EOS=1]
                }
            }
            if (tid == 0 && (s & 15) == 15) report(&progO[slice], s);
            __syncthreads();
        }
    }
}

// ---------------------------------------------------------------------------
extern "C" void kernel_launch(void* const* d_in, const int* in_sizes, int n_in,
                              void* d_out, int out_size, void* d_ws, size_t ws_size,
                              hipStream_t stream)
{
    const int*   nums = (const int*)d_in[0];
    const float* emb  = (const float*)d_in[1];
    const float* Wxh1 = (const float*)d_in[2];
    const float* Whh1 = (const float*)d_in[3];
    const float* b1   = (const float*)d_in[4];
    const float* Wxh2 = (const float*)d_in[5];
    const float* Whh2 = (const float*)d_in[6];
    const float* b2   = (const float*)d_in[7];
    const float* Wl   = (const float*)d_in[8];
    const float* bl   = (const float*)d_in[9];
    const float* T    = (const float*)d_in[10];
    float* out = (float*)d_out;

    // workspace (~6.1 MB): X1 4MB + expT 1MB + 4 rings x 256KB + prog
    float* Xbuf = (float*)d_ws;                         // [NSEQ*D]
    float* expT = Xbuf + (size_t)NSEQ * D;              // [V*V]
    uint64_t* ring1 = (uint64_t*)(expT + (size_t)V * V);
    uint64_t* ring2 = ring1 + (size_t)RING * D;
    uint64_t* ringO = ring2 + (size_t)RING * D;
    uint64_t* ringF = ringO + (size_t)RING * V;
    uint64_t* prog1 = ringF + (size_t)RING * V;         // [NB]
    uint64_t* prog2 = prog1 + NB;                       // [NB]
    uint64_t* progO = prog2 + NB;                       // [NB]

    // X1 = gather(emb, nums) @ Wxh1 + b1
    gemm_rows<8><<<NSEQ / 8, 256, 0, stream>>>(nums, emb, Wxh1, b1, Xbuf);
    // elementwise exp(T)
    prep_exp<<<V * V / 512, 512, 0, stream>>>(T, expT);
    // the whole sequential pipeline in one launch
    pipe_all<<<4 * NB, 512, 0, stream>>>(Xbuf, Whh1, Wxh2, Whh2, b2, Wl, bl,
                                         expT, ring1, ring2, ringO, ringF,
                                         prog1, prog2, progO, out);
}

// Round 7
// 3952.197 us; speedup vs baseline: 3.7235x; 1.1696x over previous
//
#include <hip/hip_runtime.h>
#include <math.h>
#include <stdint.h>

#define NSEQ 2048
#define D 512
#define V 512
#define NB 8            // column-slice blocks per pipeline stage
#define CPB 64          // D / NB
#define RING 64         // ring depth (steps)
#define RMASK (RING - 1)
#define ACK_MAGIC 0x0ACEull

// ---------------------------------------------------------------------------
// Dual-path tagged sync, NO sticky state (R6 deadlock fix).
//  fast ring: plain (workgroup-scope) store -> producer XCD's L2; sc0 load
//             (bypasses L1) hits the shared L2 iff consumer is on the SAME
//             XCD (~250cy). May be arbitrarily stale otherwise.
//  slow ring: relaxed agent-scope atomics -> IF-level, any placement (~700cy).
// Every poll iteration probes fast THEN slow, so progress is guaranteed by
// the slow path regardless of block placement; staleness only costs time.
// ---------------------------------------------------------------------------
__device__ __forceinline__ bool tag_ok(uint64_t u, uint32_t tag) {
    return (uint32_t)(u >> 32) == tag;
}
__device__ __forceinline__ float tv_val(uint64_t u) {
    return __uint_as_float((uint32_t)u);
}
__device__ __forceinline__ uint64_t ld_fast(const uint64_t* p) {
    uint64_t u;
    asm volatile("global_load_dwordx2 %0, %1, off sc0\n\ts_waitcnt vmcnt(0)"
                 : "=v"(u) : "v"(p) : "memory");
    return u;
}
__device__ __forceinline__ uint64_t ld_slow(uint64_t* p) {
    return __hip_atomic_load(p, __ATOMIC_RELAXED, __HIP_MEMORY_SCOPE_AGENT);
}
__device__ __forceinline__ void publish2(uint64_t* fp, uint64_t* sp,
                                         float v, uint32_t tag) {
    uint64_t u = ((uint64_t)tag << 32) | (uint64_t)__float_as_uint(v);
    __hip_atomic_store(fp, u, __ATOMIC_RELAXED, __HIP_MEMORY_SCOPE_WORKGROUP);
    __hip_atomic_store(sp, u, __ATOMIC_RELAXED, __HIP_MEMORY_SCOPE_AGENT);
}
__device__ __forceinline__ void publish_slow(uint64_t* sp, float v,
                                             uint32_t tag) {
    uint64_t u = ((uint64_t)tag << 32) | (uint64_t)__float_as_uint(v);
    __hip_atomic_store(sp, u, __ATOMIC_RELAXED, __HIP_MEMORY_SCOPE_AGENT);
}
// alternate fast/slow probes; slow probe guarantees progress
__device__ __forceinline__ float poll_both(uint64_t* fp, uint64_t* sp,
                                           uint32_t tag) {
    while (true) {
        uint64_t u = ld_fast(fp);
        if (tag_ok(u, tag)) return tv_val(u);
        u = ld_slow(sp);
        if (tag_ok(u, tag)) return tv_val(u);
    }
}
__device__ __forceinline__ float poll_slow(uint64_t* p, uint32_t tag) {
    while (true) {
        uint64_t u = ld_slow(p);
        if (tag_ok(u, tag)) return tv_val(u);
    }
}

// cross-stage consumer progress (flow control for ring reuse).
// Margin check: producer step sp < consumer_step - 16 + (RING-4) ->
// clobbered slot tag sp-64 is always older than anything still needed.
__device__ __forceinline__ void report(uint64_t* p, int s) {
    uint64_t u = (ACK_MAGIC << 48) | (uint32_t)s;
    __hip_atomic_store(p, u, __ATOMIC_RELAXED, __HIP_MEMORY_SCOPE_AGENT);
}
__device__ __forceinline__ void throttle(uint64_t* prog, int s, int& cached) {
    if (s - cached < RING - 4) return;
    while (true) {
        int mn = 0x7fffffff;
#pragma unroll
        for (int i = 0; i < NB; ++i) {
            uint64_t u = __hip_atomic_load(&prog[i], __ATOMIC_RELAXED,
                                           __HIP_MEMORY_SCOPE_AGENT);
            int v = ((u >> 48) == ACK_MAGIC) ? (int)(uint32_t)u : 0;
            mn = (v < mn) ? v : mn;
        }
        cached = mn;
        if (s - cached < RING - 4) return;
    }
}

__device__ __forceinline__ float fast_tanh(float x) {
    return 1.0f - 2.0f / (__expf(2.0f * x) + 1.0f);
}

__device__ __forceinline__ float mat_part(const float* sh, const float* wreg,
                                          int w) {
    const float4* v4 = (const float4*)&sh[w << 6];
    float a0 = 0.f, a1 = 0.f, a2 = 0.f, a3 = 0.f;
#pragma unroll
    for (int t = 0; t < 16; ++t) {
        float4 x = v4[t];
        a0 += x.x * wreg[4 * t + 0];
        a1 += x.y * wreg[4 * t + 1];
        a2 += x.z * wreg[4 * t + 2];
        a3 += x.w * wreg[4 * t + 3];
    }
    return (a0 + a1) + (a2 + a3);
}
__device__ __forceinline__ float mat_part2(const float* shx, const float* shh,
                                           const float* wx, const float* wh,
                                           int w) {
    const float4* x4 = (const float4*)&shx[w << 6];
    const float4* h4 = (const float4*)&shh[w << 6];
    float a0 = 0.f, a1 = 0.f, a2 = 0.f, a3 = 0.f;
#pragma unroll
    for (int t = 0; t < 16; ++t) {
        float4 xv = x4[t];
        float4 hv = h4[t];
        a0 += xv.x * wx[4 * t + 0] + hv.x * wh[4 * t + 0];
        a1 += xv.y * wx[4 * t + 1] + hv.y * wh[4 * t + 1];
        a2 += xv.z * wx[4 * t + 2] + hv.z * wh[4 * t + 2];
        a3 += xv.w * wx[4 * t + 3] + hv.w * wh[4 * t + 3];
    }
    return (a0 + a1) + (a2 + a3);
}

// ---------------------------------------------------------------------------
// X1 = gather(emb, nums) @ Wxh1 + b1
// ---------------------------------------------------------------------------
template <int TM>
__global__ void gemm_rows(const int* __restrict__ nums,
                          const float* __restrict__ emb,
                          const float* __restrict__ W,
                          const float* __restrict__ bias,
                          float* __restrict__ out)
{
    __shared__ float xs[TM][D];
    const int tid = threadIdx.x;               // 256
    const int r0 = blockIdx.x * TM;

    for (int m = 0; m < TM; ++m) {
        const float* xr = emb + (size_t)nums[r0 + m] * D;
        for (int idx = tid; idx < D; idx += 256) xs[m][idx] = xr[idx];
    }
    __syncthreads();

    const int j0 = tid, j1 = tid + 256;
    float acc0[TM], acc1[TM];
#pragma unroll
    for (int m = 0; m < TM; ++m) { acc0[m] = 0.f; acc1[m] = 0.f; }

    for (int k = 0; k < D; ++k) {
        const float w0 = W[(size_t)k * D + j0];
        const float w1 = W[(size_t)k * D + j1];
#pragma unroll
        for (int m = 0; m < TM; ++m) {
            const float x = xs[m][k];
            acc0[m] += x * w0;
            acc1[m] += x * w1;
        }
    }
    const float bb0 = bias[j0], bb1 = bias[j1];
#pragma unroll
    for (int m = 0; m < TM; ++m) {
        out[(size_t)(r0 + m) * D + j0] = acc0[m] + bb0;
        out[(size_t)(r0 + m) * D + j1] = acc1[m] + bb1;
    }
}

__global__ void prep_exp(const float* __restrict__ T, float* __restrict__ expT)
{
    const int i = blockIdx.x * 512 + threadIdx.x;
    expT[i] = __expf(T[i]);
}

// ---------------------------------------------------------------------------
// 4-stage pipeline. Launch 64 blocks; active: stage = blockIdx&7 in [0,4),
// slice = blockIdx>>3 (round-robin heuristic puts a stage's 8 blocks on one
// XCD -> fast ring works; if not, slow probes keep it correct).
// Fast rings exist ONLY for intra-stage self-recurrence (ring1/ring2/ringF).
// Cross-stage inputs (ring1->s1, ring2->s2, ringO->s3) use the slow ring,
// prefetched one step ahead so their latency hides under the matvec.
// ---------------------------------------------------------------------------
__global__ void __launch_bounds__(512, 1)
pipe_all(const float* __restrict__ X1,
         const float* __restrict__ Whh1,
         const float* __restrict__ Wxh2,
         const float* __restrict__ Whh2,
         const float* __restrict__ b2,
         const float* __restrict__ Wl,
         const float* __restrict__ bl,
         const float* __restrict__ expT,
         uint64_t* __restrict__ ring1f, uint64_t* __restrict__ ring1s,
         uint64_t* __restrict__ ring2f, uint64_t* __restrict__ ring2s,
         uint64_t* __restrict__ ringOs,
         uint64_t* __restrict__ ringFf, uint64_t* __restrict__ ringFs,
         uint64_t* __restrict__ prog1,
         uint64_t* __restrict__ prog2,
         uint64_t* __restrict__ progO,
         float* __restrict__ out)
{
    __shared__ float sh1[D];
    __shared__ float sh2[D];
    __shared__ float part[D];
    __shared__ float wmax[8];
    __shared__ float own[CPB];

    const int stage = blockIdx.x & 7;
    if (stage >= 4) return;
    const int slice = blockIdx.x >> 3;

    const int tid = threadIdx.x;      // 512
    const int w = tid >> 6, l = tid & 63;
    const int jbase = slice * CPB;
    const int lcol = (w << 3) + (l & 7);
    const int gcol = jbase + lcol;
    const bool pub = (l < 8);
    const bool ownr = (tid >= jbase) && (tid < jbase + CPB);
    int cached = 0;

    if (stage == 0) {
        float wreg[64];
#pragma unroll
        for (int t = 0; t < 64; ++t)
            wreg[t] = Whh1[(size_t)(w * 64 + t) * D + jbase + l];

        for (int s = 0; s < NSEQ; ++s) {
            const float xpre = pub ? X1[(size_t)s * D + gcol] : 0.f;
            if (s == 0)    sh1[tid] = 0.f;
            else if (ownr) sh1[tid] = own[tid - jbase];
            else           sh1[tid] = poll_both(
                               &ring1f[(size_t)((s - 1) & RMASK) * D + tid],
                               &ring1s[(size_t)((s - 1) & RMASK) * D + tid],
                               (uint32_t)(s - 1));
            __syncthreads();
            part[tid] = mat_part(sh1, wreg, w);
            __syncthreads();
            if (pub) {
                float sum = 0.f;
#pragma unroll
                for (int ww = 0; ww < 8; ++ww) sum += part[(ww << 6) + lcol];
                const float g = fast_tanh(sum + xpre);
                own[lcol] = g;
                throttle(prog1, s, cached);
                publish2(&ring1f[(size_t)(s & RMASK) * D + gcol],
                         &ring1s[(size_t)(s & RMASK) * D + gcol],
                         g, (uint32_t)s);
            }
            __syncthreads();   // protects own[] for next iteration
        }
    } else if (stage == 1) {
        float wx[64], wh[64];
#pragma unroll
        for (int t = 0; t < 64; ++t) {
            wx[t] = Wxh2[(size_t)(w * 64 + t) * D + jbase + l];
            wh[t] = Whh2[(size_t)(w * 64 + t) * D + jbase + l];
        }
        const float bpre = pub ? b2[gcol] : 0.f;
        uint64_t pre = 0;   // prefetched ring1 slow value for step s

        for (int s = 0; s < NSEQ; ++s) {
            float h1v;
            if (tag_ok(pre, (uint32_t)s)) h1v = tv_val(pre);
            else h1v = poll_slow(&ring1s[(size_t)(s & RMASK) * D + tid],
                                 (uint32_t)s);
            float h2v;
            if (s == 0)    h2v = 0.f;
            else if (ownr) h2v = own[tid - jbase];
            else           h2v = poll_both(
                               &ring2f[(size_t)((s - 1) & RMASK) * D + tid],
                               &ring2s[(size_t)((s - 1) & RMASK) * D + tid],
                               (uint32_t)(s - 1));
            sh1[tid] = h1v;
            sh2[tid] = h2v;
            __syncthreads();
            if (s + 1 < NSEQ)   // prefetch next h1; hides under matvec
                pre = ld_slow(&ring1s[(size_t)((s + 1) & RMASK) * D + tid]);
            part[tid] = mat_part2(sh1, sh2, wx, wh, w);
            __syncthreads();
            if (pub) {
                float sum = 0.f;
#pragma unroll
                for (int ww = 0; ww < 8; ++ww) sum += part[(ww << 6) + lcol];
                const float g = fast_tanh(sum + bpre);
                own[lcol] = g;
                throttle(prog2, s, cached);
                publish2(&ring2f[(size_t)(s & RMASK) * D + gcol],
                         &ring2s[(size_t)(s & RMASK) * D + gcol],
                         g, (uint32_t)s);
            }
            if (tid == 0 && (s & 15) == 15) report(&prog1[slice], s);
            __syncthreads();
        }
    } else if (stage == 2) {
        float wreg[64];
#pragma unroll
        for (int t = 0; t < 64; ++t)
            wreg[t] = Wl[(size_t)(w * 64 + t) * V + jbase + l];
        const float bpre = pub ? bl[gcol] : 0.f;
        uint64_t pre = 0;

        for (int s = 0; s < NSEQ; ++s) {
            float hv;
            if (tag_ok(pre, (uint32_t)s)) hv = tv_val(pre);
            else hv = poll_slow(&ring2s[(size_t)(s & RMASK) * D + tid],
                                (uint32_t)s);
            sh1[tid] = hv;
            __syncthreads();
            if (s + 1 < NSEQ)
                pre = ld_slow(&ring2s[(size_t)((s + 1) & RMASK) * D + tid]);
            part[tid] = mat_part(sh1, wreg, w);
            __syncthreads();
            if (pub) {
                float sum = 0.f;
#pragma unroll
                for (int ww = 0; ww < 8; ++ww) sum += part[(ww << 6) + lcol];
                throttle(progO, s, cached);
                publish_slow(&ringOs[(size_t)(s & RMASK) * V + gcol],
                             sum + bpre, (uint32_t)s);
            }
            if (tid == 0 && (s & 15) == 15) report(&prog2[slice], s);
            __syncthreads();
        }
    } else {
        // forward CRF: f_s[k] = O[s][k] + LSE_j(f_{s-1}[j] + T[j,k]);
        // out = f_{n-1}[EOS=1]  (== reference backward recursion at BOS)
        float wreg[64];
#pragma unroll
        for (int t = 0; t < 64; ++t)
            wreg[t] = expT[(size_t)(w * 64 + t) * V + jbase + l];

        float creg = (tid == 0) ? poll_slow(&ringOs[0], 0u) : -1e30f;
        uint64_t preO = 0;

        for (int s = 1; s < NSEQ; ++s) {
            if (s > 1) {
                if (ownr) creg = own[tid - jbase];
                else      creg = poll_both(
                              &ringFf[(size_t)((s - 1) & RMASK) * V + tid],
                              &ringFs[(size_t)((s - 1) & RMASK) * V + tid],
                              (uint32_t)(s - 1));
            }
            float opre = 0.f;
            if (pub) {
                if (tag_ok(preO, (uint32_t)s)) opre = tv_val(preO);
                else opre = poll_slow(&ringOs[(size_t)(s & RMASK) * V + gcol],
                                      (uint32_t)s);
            }

            float mx = creg;
#pragma unroll
            for (int off = 32; off > 0; off >>= 1)
                mx = fmaxf(mx, __shfl_xor(mx, off, 64));
            if (l == 0) wmax[w] = mx;
            __syncthreads();
            float M = wmax[0];
#pragma unroll
            for (int ww = 1; ww < 8; ++ww) M = fmaxf(M, wmax[ww]);

            sh1[tid] = __expf(creg - M);
            __syncthreads();
            if (pub && s + 1 < NSEQ)
                preO = ld_slow(&ringOs[(size_t)((s + 1) & RMASK) * V + gcol]);
            part[tid] = mat_part(sh1, wreg, w);
            __syncthreads();

            if (pub) {
                float sum = 0.f;
#pragma unroll
                for (int ww = 0; ww < 8; ++ww) sum += part[(ww << 6) + lcol];
                const float cn = opre + M + __logf(sum);
                if (s < NSEQ - 1) {
                    own[lcol] = cn;
                    publish2(&ringFf[(size_t)(s & RMASK) * V + gcol],
                             &ringFs[(size_t)(s & RMASK) * V + gcol],
                             cn, (uint32_t)s);
                } else if (gcol == 1) {
                    out[0] = cn;           // f_{n-1}[EOS=1]
                }
            }
            if (tid == 0 && (s & 15) == 15) report(&progO[slice], s);
            __syncthreads();
        }
    }
}

// ---------------------------------------------------------------------------
extern "C" void kernel_launch(void* const* d_in, const int* in_sizes, int n_in,
                              void* d_out, int out_size, void* d_ws, size_t ws_size,
                              hipStream_t stream)
{
    const int*   nums = (const int*)d_in[0];
    const float* emb  = (const float*)d_in[1];
    const float* Wxh1 = (const float*)d_in[2];
    const float* Whh1 = (const float*)d_in[3];
    const float* b1   = (const float*)d_in[4];
    const float* Wxh2 = (const float*)d_in[5];
    const float* Whh2 = (const float*)d_in[6];
    const float* b2   = (const float*)d_in[7];
    const float* Wl   = (const float*)d_in[8];
    const float* bl   = (const float*)d_in[9];
    const float* T    = (const float*)d_in[10];
    float* out = (float*)d_out;

    // workspace (~7 MB): X1 + expT + 7 rings (256KB each) + progress
    float* Xbuf = (float*)d_ws;                         // [NSEQ*D]
    float* expT = Xbuf + (size_t)NSEQ * D;              // [V*V]
    uint64_t* ring1f = (uint64_t*)(expT + (size_t)V * V);
    uint64_t* ring1s = ring1f + (size_t)RING * D;
    uint64_t* ring2f = ring1s + (size_t)RING * D;
    uint64_t* ring2s = ring2f + (size_t)RING * D;
    uint64_t* ringOs = ring2s + (size_t)RING * D;
    uint64_t* ringFf = ringOs + (size_t)RING * V;
    uint64_t* ringFs = ringFf + (size_t)RING * V;
    uint64_t* prog1  = ringFs + (size_t)RING * V;       // [NB]
    uint64_t* prog2  = prog1 + NB;                      // [NB]
    uint64_t* progO  = prog2 + NB;                      // [NB]

    gemm_rows<8><<<NSEQ / 8, 256, 0, stream>>>(nums, emb, Wxh1, b1, Xbuf);
    prep_exp<<<V * V / 512, 512, 0, stream>>>(T, expT);
    pipe_all<<<64, 512, 0, stream>>>(Xbuf, Whh1, Wxh2, Whh2, b2, Wl, bl, expT,
                                     ring1f, ring1s, ring2f, ring2s, ringOs,
                                     ringFf, ringFs, prog1, prog2, progO, out);
}